// Round 1
// 1165.053 us; speedup vs baseline: 1.2534x; 1.2534x over previous
//
#include <hip/hip_runtime.h>
#include <stdint.h>

// FusedGPTQMLP on MI355X (gfx950).
// Round 7: port GEMM to the 256x256 8-phase schedule (T3+T4 counted vmcnt,
// T5 setprio, T2 swizzle kept, T1 bijective XCD swizzle). 512 thr / 8 waves,
// 128 KiB LDS double buffer, loads never drained to vmcnt(0) in the K-loop.
// ws: xb [M,HIDDEN] bf16 | gi [MC,INTER] bf16 | wb weight chunk (adaptive).

#define HIDDEN 4096
#define INTER  11008
#define BM 256
#define BN 256
#define BK 64

typedef __bf16 bf16x8 __attribute__((ext_vector_type(8)));
typedef float f32x4 __attribute__((ext_vector_type(4)));

__device__ __forceinline__ ushort f2bf_rne(float f) {
  uint32_t u = __float_as_uint(f);
  u += 0x7FFFu + ((u >> 16) & 1u);
  return (ushort)(u >> 16);
}

__device__ __forceinline__ float bf2f(ushort h) {
  return __uint_as_float(((uint32_t)h) << 16);
}

// fp32 -> bf16 bulk convert, 4 elements/thread.
__global__ void f32_to_bf16_kernel(const float* __restrict__ src,
                                   ushort* __restrict__ dst, int n4) {
  const int i = blockIdx.x * 256 + threadIdx.x;
  if (i < n4) {
    const float4 v = ((const float4*)src)[i];
    ushort4 o;
    o.x = f2bf_rne(v.x); o.y = f2bf_rne(v.y);
    o.z = f2bf_rne(v.z); o.w = f2bf_rne(v.w);
    ((ushort4*)dst)[i] = o;
  }
}

// Dequant qweight[k8][n] (8 k-nibbles per int32) into packet layout:
// Bp[(k8*nc + n_local)*8 + j] = W[k8*8+j][n0+n_local], bf16. Scales fp32.
__global__ void dequant_kernel(const int32_t* __restrict__ qw,
                               const float* __restrict__ sc,
                               const int32_t* __restrict__ zr,
                               ushort* __restrict__ Bp,
                               int Nfull, int n0, int nc) {
  const int n_local = blockIdx.x * 128 + threadIdx.x;
  const int k8 = blockIdx.y;
  const int n = n0 + n_local;
  const int g = k8 >> 4;  // groupsize 128 => 16 k8-rows per group
  const uint32_t q = (uint32_t)qw[(size_t)k8 * Nfull + n];
  const float s = sc[(size_t)g * Nfull + n];
  const uint32_t zv = (uint32_t)zr[(size_t)g * (Nfull >> 3) + (n >> 3)];
  const int z1 = (int)((zv >> ((n & 7) * 4)) & 15u) + 1;
  union { ushort h[8]; uint4 v; } o;
#pragma unroll
  for (int j = 0; j < 8; j++) {
    const int qi = (int)((q >> (4 * j)) & 15u) - z1;  // (q - (z+1)), exact int
    o.h[j] = f2bf_rne((float)qi * s);
  }
  *(uint4*)(Bp + ((size_t)k8 * nc + n_local) * 8) = o.v;
}

#define GL_LDS(gp, lp)                                                        \
  __builtin_amdgcn_global_load_lds(                                           \
      (const __attribute__((address_space(1))) uint32_t*)(gp),                \
      (__attribute__((address_space(3))) uint32_t*)(lp), 16, 0, 0)
// barrier + compiler memory fence so LDS reads can't hoist into the
// vmcnt->barrier window (cross-wave staging visibility).
#define BAR()  do { __builtin_amdgcn_s_barrier(); asm volatile("" ::: "memory"); } while (0)
#define WVM4() asm volatile("s_waitcnt vmcnt(4)" ::: "memory")
#define WVM0() asm volatile("s_waitcnt vmcnt(0)" ::: "memory")
#define WLG0() asm volatile("s_waitcnt lgkmcnt(0)" ::: "memory")

// C[m, n] = A[m, :] @ W[:, n] over this chunk's nc columns.
// A: bf16 [rows, lda] (pre-offset). Bp: packets [K/8][nc][8] bf16.
// MODE 0: C bf16 = result. MODE 1: C bf16 = silu(C_old) * result (SwiGLU).
// MODE 2: C fp32 = result (final output).
// 256x256 tile, BK=64, 8 waves (2M x 4N), per-wave output 128x64 with
// interleaved row mapping row(i) = (i>>2)*128 + (i&3)*32 + wm*16 so each
// staged half-tile's first use is as late as possible (enables vmcnt(4)).
// A tile LDS is XOR-swizzled: packet p of row m at slot (p ^ (m&7)), achieved
// by pre-swizzling the per-lane global source (linear LDS dest).
template <int MODE>
__launch_bounds__(512, 2)
__global__ void gemm_bt_kernel(const ushort* __restrict__ A,
                               const ushort* __restrict__ Bp,
                               void* __restrict__ Cv,
                               int K, int nc, int lda, int ldc) {
  __shared__ ushort sAs[2][BM * BK];           // 2 x 32 KB
  __shared__ ushort sBs[2][(BK / 8) * BN * 8]; // 2 x 32 KB

  const int tid = threadIdx.x;
  const int w = tid >> 6;
  const int lane = tid & 63;
  const int l16 = lane & 15;
  const int quad = lane >> 4;
  const int wm16 = (w >> 2) * 16;   // 2 waves along M
  const int wn = (w & 3) * 64;      // 4 waves along N

  // Bijective XCD-aware block swizzle (m204 form).
  const int gx = gridDim.x;
  const int nwg = gx * (int)gridDim.y;
  const int orig = blockIdx.y * gx + blockIdx.x;
  const int q8 = nwg >> 3, r8 = nwg & 7;
  const int xcd = orig & 7, sidx = orig >> 3;
  const int wg = (xcd < r8 ? xcd * (q8 + 1) : r8 * (q8 + 1) + (xcd - r8) * q8) + sidx;
  const int m0 = (wg / gx) * BM;
  const int bn0 = (wg % gx) * BN;

  // Staging lane geometry.
  const int arow = tid >> 3;                      // 0..63 within 64-row slab
  const int apk8 = ((tid & 7) ^ (arow & 7)) * 8;  // swizzled source packet
  const int bpr = tid >> 8;                       // 0..1 packet-row in slab
  const int bcol = tid & 255;
  const ushort* aSrc = A + (size_t)(m0 + arow) * lda + apk8;
  const ushort* bSrc = Bp + ((size_t)bpr * nc + bn0 + bcol) * 8;

  f32x4 acc[8][4];
#pragma unroll
  for (int a = 0; a < 8; a++)
#pragma unroll
    for (int j = 0; j < 4; j++) acc[a][j] = (f32x4){0.f, 0.f, 0.f, 0.f};

  const int NT = K / BK;

#define STAGE_A(r, buf, kt) \
  GL_LDS(aSrc + (size_t)(r) * 64 * lda + (kt), (buf) + (r) * 4096 + w * 512)
#define STAGE_B(r, buf, kp) \
  GL_LDS(bSrc + ((kp) + (size_t)(r) * 2) * (size_t)nc * 8, (buf) + (r) * 4096 + w * 512)

  // Prologue: stage tile 0 in stream order A0,B0,A1,B1 (matches loop order).
  {
    ushort* sAn = sAs[0];
    ushort* sBn = sBs[0];
    STAGE_A(0, sAn, (size_t)0); STAGE_A(1, sAn, (size_t)0);  // A-half0
    STAGE_B(0, sBn, (size_t)0); STAGE_B(1, sBn, (size_t)0);  // B-kk0
    STAGE_A(2, sAn, (size_t)0); STAGE_A(3, sAn, (size_t)0);  // A-half1
    STAGE_B(2, sBn, (size_t)0); STAGE_B(3, sBn, (size_t)0);  // B-kk1
  }

#pragma unroll 1
  for (int t = 0; t < NT; ++t) {
    const ushort* sAc = sAs[t & 1];
    const ushort* sBc = sBs[t & 1];
    ushort* sAn = sAs[(t & 1) ^ 1];
    ushort* sBn = sBs[(t & 1) ^ 1];
    const int tn = (t + 1 < NT) ? t + 1 : t;  // clamp: re-stage last tile
    const size_t ktn = (size_t)tn * BK;
    const size_t kpn = (size_t)tn * 8;

    // Boundary: A0,B0 of this tile landed; A1,B1 may still be in flight.
    WVM4(); BAR();

    bf16x8 af[4], bf[4];
    const ushort* pA0 = sAc + (size_t)(wm16 + l16) * 64 + ((quad ^ (l16 & 7)) * 8);
    const ushort* pA1 = sAc + (size_t)(wm16 + l16) * 64 + (((4 ^ quad) ^ (l16 & 7)) * 8);
    const ushort* pB0 = sBc + ((size_t)(quad * 256) + wn + l16) * 8;
    const ushort* pB1 = sBc + ((size_t)((4 + quad) * 256) + wn + l16) * 8;

    // ---- PH1: A-half0 x B-kk0 ; stage next A-half0 ----
#pragma unroll
    for (int i = 0; i < 4; i++) af[i] = *(const bf16x8*)(pA0 + i * 2048);
#pragma unroll
    for (int j = 0; j < 4; j++) bf[j] = *(const bf16x8*)(pB0 + j * 128);
    STAGE_A(0, sAn, ktn); STAGE_A(1, sAn, ktn);
    BAR(); WLG0();
    __builtin_amdgcn_s_setprio(1);
#pragma unroll
    for (int i = 0; i < 4; i++)
#pragma unroll
      for (int j = 0; j < 4; j++)
        acc[i][j] = __builtin_amdgcn_mfma_f32_16x16x32_bf16(af[i], bf[j], acc[i][j], 0, 0, 0);
    __builtin_amdgcn_s_setprio(0);
    WVM4();  // A-half1 of this tile landed
    BAR();

    // ---- PH2: A-half1 x B-kk0 (bf reused) ; stage next B-kk0 ----
#pragma unroll
    for (int i = 0; i < 4; i++) af[i] = *(const bf16x8*)(pA0 + 128 * 64 + i * 2048);
    STAGE_B(0, sBn, kpn); STAGE_B(1, sBn, kpn);
    BAR(); WLG0();
    __builtin_amdgcn_s_setprio(1);
#pragma unroll
    for (int i = 0; i < 4; i++)
#pragma unroll
      for (int j = 0; j < 4; j++)
        acc[4 + i][j] = __builtin_amdgcn_mfma_f32_16x16x32_bf16(af[i], bf[j], acc[4 + i][j], 0, 0, 0);
    __builtin_amdgcn_s_setprio(0);
    WVM4();  // B-kk1 of this tile landed
    BAR();

    // ---- PH3: A-half0 x B-kk1 ; stage next A-half1 ----
#pragma unroll
    for (int i = 0; i < 4; i++) af[i] = *(const bf16x8*)(pA1 + i * 2048);
#pragma unroll
    for (int j = 0; j < 4; j++) bf[j] = *(const bf16x8*)(pB1 + j * 128);
    STAGE_A(2, sAn, ktn); STAGE_A(3, sAn, ktn);
    BAR(); WLG0();
    __builtin_amdgcn_s_setprio(1);
#pragma unroll
    for (int i = 0; i < 4; i++)
#pragma unroll
      for (int j = 0; j < 4; j++)
        acc[i][j] = __builtin_amdgcn_mfma_f32_16x16x32_bf16(af[i], bf[j], acc[i][j], 0, 0, 0);
    __builtin_amdgcn_s_setprio(0);
    BAR();  // no vmcnt here

    // ---- PH4: A-half1 x B-kk1 (bf reused) ; stage next B-kk1 ----
#pragma unroll
    for (int i = 0; i < 4; i++) af[i] = *(const bf16x8*)(pA1 + 128 * 64 + i * 2048);
    STAGE_B(2, sBn, kpn); STAGE_B(3, sBn, kpn);
    BAR(); WLG0();
    __builtin_amdgcn_s_setprio(1);
#pragma unroll
    for (int i = 0; i < 4; i++)
#pragma unroll
      for (int j = 0; j < 4; j++)
        acc[4 + i][j] = __builtin_amdgcn_mfma_f32_16x16x32_bf16(af[i], bf[j], acc[4 + i][j], 0, 0, 0);
    __builtin_amdgcn_s_setprio(0);
    // closing vmcnt+barrier folded into next iteration's loop top
  }
  WVM0();  // drain trailing (re-)staged loads before epilogue / endpgm

  // Epilogue. C/D layout: col = lane&15, row = quad*4 + reg.
  // Row mapping: gm = m0 + (a>>2)*128 + (a&3)*32 + wm16 + quad*4 + r.
#pragma unroll
  for (int a = 0; a < 8; a++) {
    const int gmb = m0 + (a >> 2) * 128 + (a & 3) * 32 + wm16 + quad * 4;
#pragma unroll
    for (int r = 0; r < 4; r++) {
      const int gm = gmb + r;
      if (MODE == 2) {
        float* crow = (float*)Cv + (size_t)gm * ldc + bn0 + wn;
#pragma unroll
        for (int j = 0; j < 4; j++) crow[j * 16 + l16] = acc[a][j][r];
      } else {
        ushort* crow = (ushort*)Cv + (size_t)gm * ldc + bn0 + wn;
#pragma unroll
        for (int j = 0; j < 4; j++) {
          float v = acc[a][j][r];
          if (MODE == 1) {
            const float gv = bf2f(crow[j * 16 + l16]);     // gate (bf16)
            v = (gv / (1.0f + __expf(-gv))) * v;           // silu(gate) * up
          }
          crow[j * 16 + l16] = f2bf_rne(v);
        }
      }
    }
  }
}

extern "C" void kernel_launch(void* const* d_in, const int* in_sizes, int n_in,
                              void* d_out, int out_size, void* d_ws, size_t ws_size,
                              hipStream_t stream) {
  (void)n_in; (void)out_size;
  const float*   x   = (const float*)d_in[0];    // fp32 [4096, 4096]
  const int32_t* gq  = (const int32_t*)d_in[1];  // [512, 11008]
  const float*   gs  = (const float*)d_in[2];    // fp32 [32, 11008]
  const int32_t* gz  = (const int32_t*)d_in[3];  // [32, 1376]
  const int32_t* uq  = (const int32_t*)d_in[4];
  const float*   us  = (const float*)d_in[5];
  const int32_t* uz  = (const int32_t*)d_in[6];
  const int32_t* dq  = (const int32_t*)d_in[7];  // [1376, 4096]
  const float*   dsc = (const float*)d_in[8];    // fp32 [86, 4096]
  const int32_t* dz  = (const int32_t*)d_in[9];  // [86, 512]
  float* outp = (float*)d_out;                   // fp32 [4096, 4096]

  const int M = in_sizes[0] / HIDDEN;            // 4096

  // ---- ws-size-adaptive plan (all scratch strictly inside d_ws) ----
  const size_t W = ws_size;
  const size_t col12 = (size_t)HIDDEN * 2;   // 8192 B per dequant col (K=HIDDEN)
  const size_t col3  = (size_t)INTER * 2;    // 22016 B per dequant col (K=INTER)
  const size_t xb_bytes = (size_t)M * HIDDEN * 2;   // 33.5 MB
  int MC = 256;
  for (int cand = M; cand >= 256; cand >>= 1) {
    if (xb_bytes + (size_t)cand * INTER * 2 + col3 * 256 <= W) { MC = cand; break; }
  }
  ushort* xb = (ushort*)d_ws;                              // [M, HIDDEN] bf16
  ushort* gi = xb + (size_t)M * HIDDEN;                    // [MC, INTER] bf16
  ushort* wb = gi + (size_t)MC * INTER;                    // weight chunk
  const size_t used = xb_bytes + (size_t)MC * INTER * 2;
  const size_t wbuf = (W > used) ? W - used : 0;
  int NC12 = (int)(wbuf / col12); NC12 &= ~255;
  if (NC12 < 256) NC12 = 256;
  if (NC12 > INTER) NC12 = INTER;            // 11008 = 43*256
  int NC3 = (int)(wbuf / col3); NC3 &= ~255;
  if (NC3 < 256) NC3 = 256;
  if (NC3 > HIDDEN) NC3 = HIDDEN;

  // Convert x (fp32) -> xb (bf16) once.
  const int n4 = M * HIDDEN / 4;
  f32_to_bf16_kernel<<<(n4 + 255) / 256, 256, 0, stream>>>(x, xb, n4);

  for (int m0 = 0; m0 < M; m0 += MC) {
    const ushort* xm = xb + (size_t)m0 * HIDDEN;
    // Phase 1: gate = x @ Wg   (into gi, bf16)
    for (int n0 = 0; n0 < INTER; ) {
      int nc = INTER - n0; if (nc > NC12) nc = NC12;
      dequant_kernel<<<dim3(nc / 128, HIDDEN / 8), 128, 0, stream>>>(
          gq, gs, gz, wb, INTER, n0, nc);
      gemm_bt_kernel<0><<<dim3(nc / BN, MC / BM), 512, 0, stream>>>(
          xm, wb, gi + n0, HIDDEN, nc, HIDDEN, INTER);
      n0 += nc;
    }
    // Phase 2: inter = silu(gate) * (x @ Wu)   (in place over gi)
    for (int n0 = 0; n0 < INTER; ) {
      int nc = INTER - n0; if (nc > NC12) nc = NC12;
      dequant_kernel<<<dim3(nc / 128, HIDDEN / 8), 128, 0, stream>>>(
          uq, us, uz, wb, INTER, n0, nc);
      gemm_bt_kernel<1><<<dim3(nc / BN, MC / BM), 512, 0, stream>>>(
          xm, wb, gi + n0, HIDDEN, nc, HIDDEN, INTER);
      n0 += nc;
    }
    // Phase 3: out = inter @ Wd   (fp32 out)
    for (int n0 = 0; n0 < HIDDEN; ) {
      int nc = HIDDEN - n0; if (nc > NC3) nc = NC3;
      dequant_kernel<<<dim3(nc / 128, INTER / 8), 128, 0, stream>>>(
          dq, dsc, dz, wb, HIDDEN, n0, nc);
      gemm_bt_kernel<2><<<dim3(nc / BN, MC / BM), 512, 0, stream>>>(
          gi, wb, (void*)(outp + (size_t)m0 * HIDDEN + n0), INTER, nc, INTER, HIDDEN);
      n0 += nc;
    }
  }
}